// Round 4
// baseline (473.078 us; speedup 1.0000x reference)
//
#include <hip/hip_runtime.h>
#include <hip/hip_cooperative_groups.h>

namespace cg = cooperative_groups;

#define B 32
#define S 3136
#define C 256
#define W 98            // 32-bit words per channel: 98*32 = 3136
#define THRESH 1568     // cnt >= S*0.5 -> percent >= SIMILARITY -> kill
#define TC 16           // channels per mask task -> 32*16 = 512 D-tasks (one grid round)
#define NBLK 768        // 3 blocks/CU * 256 CU; validated by cooperative launch
#define NWTASK (B * W)          // 3136 word tasks (32 rows each)
#define NDTASK (B * (C / TC))   // 512 mask tasks

typedef float fvec4 __attribute__((ext_vector_type(4)));

// Single cooperative kernel. Phases separated by grid.sync() — fully
// stateless (no workspace counters), so rocprof dispatch-replay and any
// re-run ordering are safe. partial/bits are fully rewritten before each
// read within one launch.
__global__ __launch_bounds__(256, 3) void k_fused(const float* __restrict__ x,
                                                  float* __restrict__ partial,
                                                  float* __restrict__ meanv,
                                                  unsigned int* __restrict__ bits,
                                                  float* __restrict__ out) {
    cg::grid_group grid = cg::this_grid();
    const int tid = threadIdx.x;
    const int rg  = tid >> 6;   // row-group 0..3 (8 rows each within a 32-row word)
    const int c4  = tid & 63;   // float4 group within channel dim
    __shared__ float4 smf[256];
    __shared__ uint4  smb[4][64];
    __shared__ unsigned int sh_km;

    // ---------------- phase A: per-word partial channel sums ----------------
    for (int t = blockIdx.x; t < NWTASK; t += NBLK) {
        const int b = t / W;
        const int w = t - b * W;
        const float4* p = (const float4*)(x + ((size_t)b * S + (size_t)w * 32 + rg * 8) * C) + c4;
        float4 s = make_float4(0.f, 0.f, 0.f, 0.f);
#pragma unroll
        for (int k = 0; k < 8; ++k) {
            float4 v = p[(size_t)k * (C / 4)];
            s.x += v.x; s.y += v.y; s.z += v.z; s.w += v.w;
        }
        smf[tid] = s;
        __syncthreads();
        if (rg == 0) {
            float4 a = smf[c4], b2 = smf[c4 + 64], cc = smf[c4 + 128], d = smf[c4 + 192];
            float4 tt;
            tt.x = a.x + b2.x + cc.x + d.x;
            tt.y = a.y + b2.y + cc.y + d.y;
            tt.z = a.z + b2.z + cc.z + d.z;
            tt.w = a.w + b2.w + cc.w + d.w;
            ((float4*)(partial + (size_t)t * C))[c4] = tt;
        }
        __syncthreads();
    }

    grid.sync();

    // ---------------- mean: 32 blocks, one batch each ----------------
    if (blockIdx.x < B) {
        const int b = blockIdx.x;
        const float* pp = partial + (size_t)b * W * C + tid;
        float ms = 0.f;
        for (int k = 0; k < W; ++k) ms += pp[(size_t)k * C];
        meanv[(size_t)b * C + tid] = ms * (1.0f / (float)S);
    }

    grid.sync();

    // ---------------- phase C: bits + out = x copy ----------------
    for (int t = blockIdx.x; t < NWTASK; t += NBLK) {
        const int b = t / W;
        const int w = t - b * W;
        const float4 m = ((const float4*)(meanv + (size_t)b * C))[c4];
        const size_t rowbase = ((size_t)b * S + (size_t)w * 32 + (size_t)(rg * 8)) * C;
        const float4* p  = (const float4*)(x + rowbase) + c4;
        fvec4*       po  = (fvec4*)(out + rowbase) + c4;
        unsigned int f0 = 0, f1 = 0, f2 = 0, f3 = 0;
#pragma unroll
        for (int k = 0; k < 8; ++k) {
            float4 v = p[(size_t)k * (C / 4)];
            fvec4 nv; nv.x = v.x; nv.y = v.y; nv.z = v.z; nv.w = v.w;
            __builtin_nontemporal_store(nv, po + (size_t)k * (C / 4));  // out = x; keep x hot in L3
            const int sh = rg * 8 + k;
            f0 |= (v.x > m.x) ? (1u << sh) : 0u;
            f1 |= (v.y > m.y) ? (1u << sh) : 0u;
            f2 |= (v.z > m.z) ? (1u << sh) : 0u;
            f3 |= (v.w > m.w) ? (1u << sh) : 0u;
        }
        uint4 fb; fb.x = f0; fb.y = f1; fb.z = f2; fb.w = f3;
        smb[rg][c4] = fb;
        __syncthreads();
        if (rg == 0) {
            uint4 q0 = smb[0][c4], q1 = smb[1][c4], q2 = smb[2][c4], q3 = smb[3][c4];
            uint4 ob;
            ob.x = q0.x | q1.x | q2.x | q3.x;
            ob.y = q0.y | q1.y | q2.y | q3.y;
            ob.z = q0.z | q1.z | q2.z | q3.z;
            ob.w = q0.w | q1.w | q2.w | q3.w;
            ((uint4*)(bits + (size_t)t * C))[c4] = ob;
        }
        __syncthreads();
    }

    grid.sync();

    // ---------------- phase D: pairwise popcount mask + fixup ----------------
    for (int t = blockIdx.x; t < NDTASK; t += NBLK) {
        const int b  = t >> 4;            // 16 groups per batch (C/TC)
        const int c0 = (t & 15) * TC;
        const unsigned int* bb = bits + (size_t)b * (W * C);
        const int j = tid;
        unsigned int cnt[TC];
#pragma unroll
        for (int q = 0; q < TC; ++q) cnt[q] = 0;
#pragma unroll 2
        for (int w = 0; w < W; ++w) {
            const unsigned int bj = bb[(size_t)w * C + j];     // coalesced
            const unsigned int* bc = bb + (size_t)w * C + c0;  // uniform -> s_load
#pragma unroll
            for (int q = 0; q < TC; ++q) cnt[q] += __popc(bj & bc[q]);
        }
        if (tid == 0) sh_km = 0u;
        __syncthreads();
        unsigned int kill = 0;
#pragma unroll
        for (int q = 0; q < TC; ++q)
            if ((c0 + q) != j && cnt[q] >= THRESH) kill |= (1u << q);
        if (kill) atomicOr(&sh_km, kill);
        __syncthreads();
        const unsigned int k2 = sh_km;
        __syncthreads();                  // protect sh_km reset on next task
        if (k2 == 0u) continue;           // uniform; common fast path
#pragma unroll
        for (int q = 0; q < TC; ++q) {
            if ((k2 >> q) & 1u) {
                float* col = out + (size_t)b * S * C + (c0 + q);
                for (int row = j; row < S; row += 256)
                    col[(size_t)row * C] = 0.0f;
            }
        }
    }
}

extern "C" void kernel_launch(void* const* d_in, const int* in_sizes, int n_in,
                              void* d_out, int out_size, void* d_ws, size_t ws_size,
                              hipStream_t stream) {
    const float* x = (const float*)d_in[0];
    float* out = (float*)d_out;

    // ws layout: partial [3136][256] f32 (3.21 MB) | mean [32][256] f32 (32 KB)
    //            bits [3136][256] u32 (3.21 MB). No init required.
    float* partial     = (float*)d_ws;
    float* meanv       = partial + (size_t)NWTASK * C;
    unsigned int* bits = (unsigned int*)(meanv + (size_t)B * C);

    void* kargs[] = {(void*)&x, (void*)&partial, (void*)&meanv, (void*)&bits, (void*)&out};
    hipLaunchCooperativeKernel((const void*)k_fused, dim3(NBLK), dim3(256), kargs, 0, stream);
}

// Round 5
// 219.956 us; speedup vs baseline: 2.1508x; 2.1508x over previous
//
#include <hip/hip_runtime.h>

#define B 32
#define S 3136
#define C 256
#define W 98            // 32-bit words per channel: 98*32 = 3136
#define THRESH 1568     // cnt >= S*0.5 -> percent >= SIMILARITY -> kill
#define TC 8            // channels per k_mask block
#define NCHUNK 56       // spatial chunks for mean partials (56 rows each) -> 1792 blocks = 7/CU exact
#define CROWS 56

typedef float fvec4 __attribute__((ext_vector_type(4)));  // native vector for nontemporal builtins

// ---- pass 1: single read of x does double duty: NT-copy out=x AND
// per-chunk partial channel sums. Moves the 103 MB out-store into the
// pass that already holds x in registers; pass 3 then only writes bits.
__global__ __launch_bounds__(256) void k_mean_copy(const float* __restrict__ x,
                                                   float* __restrict__ out,
                                                   float* __restrict__ partial) {
    const int b = blockIdx.x;         // 0..31
    const int chunk = blockIdx.y;     // 0..55 (56 rows each)
    const int c4 = threadIdx.x & 63;  // float4 group within channel dim
    const int r  = threadIdx.x >> 6;  // 0..3
    const size_t base = ((size_t)b * S + (size_t)chunk * CROWS + r) * C;
    const float4* p  = (const float4*)(x + base) + c4;
    fvec4*       po  = (fvec4*)(out + base) + c4;
    float4 sum = make_float4(0.f, 0.f, 0.f, 0.f);
#pragma unroll
    for (int k = 0; k < CROWS / 4; ++k) {   // rows r, r+4, ..., r+52 (14 iters)
        float4 v = p[(size_t)k * 4 * (C / 4)];
        fvec4 nv; nv.x = v.x; nv.y = v.y; nv.z = v.z; nv.w = v.w;
        __builtin_nontemporal_store(nv, po + (size_t)k * 4 * (C / 4));  // out = x
        sum.x += v.x; sum.y += v.y; sum.z += v.z; sum.w += v.w;
    }
    __shared__ float4 sm[256];
    sm[threadIdx.x] = sum;
    __syncthreads();
    if (r == 0) {
        float4 a = sm[c4], b2 = sm[c4 + 64], c_ = sm[c4 + 128], d = sm[c4 + 192];
        float4 t;
        t.x = a.x + b2.x + c_.x + d.x;
        t.y = a.y + b2.y + c_.y + d.y;
        t.z = a.z + b2.z + c_.z + d.z;
        t.w = a.w + b2.w + c_.w + d.w;
        ((float4*)(partial + ((size_t)b * NCHUNK + chunk) * C))[c4] = t;
    }
}

// ---- pass 1.5: tiny reduction partial -> mean[b][c] (pre-divided by S) ----
__global__ __launch_bounds__(256) void k_mean_final(const float* __restrict__ partial,
                                                    float* __restrict__ mean) {
    const int b = blockIdx.x;     // 0..31
    const int c = threadIdx.x;    // 0..255
    const float* p = partial + (size_t)b * NCHUNK * C + c;
    float s = 0.f;
#pragma unroll
    for (int k = 0; k < NCHUNK; ++k) s += p[(size_t)k * C];
    mean[(size_t)b * C + c] = s * (1.0f / (float)S);
}

// ---- pass 2: bits only. x is L3-resident from pass 1; writes 3.2 MB ----
__global__ __launch_bounds__(64) void k_bits(const float* __restrict__ x,
                                             const float* __restrict__ mean,
                                             unsigned int* __restrict__ bits) {
    const int b  = blockIdx.x;        // 0..31
    const int w  = blockIdx.y;        // 0..97
    const int c4 = threadIdx.x;       // 0..63

    const float4 m = ((const float4*)(mean + (size_t)b * C))[c4];

    const size_t rowbase = ((size_t)b * S + (size_t)w * 32) * C;
    const float4* p = (const float4*)(x + rowbase) + c4;
    unsigned int w0 = 0, w1 = 0, w2 = 0, w3 = 0;
#pragma unroll
    for (int k = 0; k < 32; ++k) {
        float4 v = p[(size_t)k * (C / 4)];
        w0 |= (v.x > m.x) ? (1u << k) : 0u;
        w1 |= (v.y > m.y) ? (1u << k) : 0u;
        w2 |= (v.z > m.z) ? (1u << k) : 0u;
        w3 |= (v.w > m.w) ? (1u << k) : 0u;
    }
    uint4 ob; ob.x = w0; ob.y = w1; ob.z = w2; ob.w = w3;
    ((uint4*)(bits + ((size_t)b * W + w) * C))[c4] = ob;
}

// ---- pass 3: pairwise co-live via popcount + in-place fixup of out ----
// out already holds x (from pass 1). Common case: all live, no writes.
__global__ __launch_bounds__(256) void k_mask_fix(const unsigned int* __restrict__ bits,
                                                  float* __restrict__ out) {
    const int b  = blockIdx.x;          // 0..31
    const int c0 = blockIdx.y * TC;     // channel group this block decides
    const int j  = threadIdx.x;         // partner channel
    const unsigned int* bb = bits + (size_t)b * (W * C);

    unsigned int cnt[TC];
#pragma unroll
    for (int t = 0; t < TC; ++t) cnt[t] = 0;

#pragma unroll 2
    for (int w = 0; w < W; ++w) {
        const unsigned int bj = bb[(size_t)w * C + j];        // coalesced vload
        const unsigned int* bc = bb + (size_t)w * C + c0;     // uniform -> s_load
#pragma unroll
        for (int t = 0; t < TC; ++t)
            cnt[t] += __popc(bj & bc[t]);
    }

    __shared__ unsigned int km;
    if (j == 0) km = 0u;
    __syncthreads();

    unsigned int kill = 0;
#pragma unroll
    for (int t = 0; t < TC; ++t)
        if ((c0 + t) != j && cnt[t] >= THRESH) kill |= (1u << t);
    if (kill) atomicOr(&km, kill);
    __syncthreads();

    const unsigned int k2 = km;
    if (k2 == 0u) return;               // all 8 channels live -> done (fast path)

    // zero killed channels: thread j covers rows j, j+256, ...
#pragma unroll
    for (int t = 0; t < TC; ++t) {
        if ((k2 >> t) & 1u) {
            float* col = out + (size_t)b * S * C + (c0 + t);
            for (int row = j; row < S; row += 256)
                col[(size_t)row * C] = 0.0f;
        }
    }
}

extern "C" void kernel_launch(void* const* d_in, const int* in_sizes, int n_in,
                              void* d_out, int out_size, void* d_ws, size_t ws_size,
                              hipStream_t stream) {
    const float* x = (const float*)d_in[0];
    float* out = (float*)d_out;

    // workspace layout (no init required — every word fully overwritten
    // before first read, with a kernel boundary between write and read)
    float* partial     = (float*)d_ws;                                      // 1.83 MB
    float* meanv       = partial + (size_t)B * NCHUNK * C;                  // 32 KB
    unsigned int* bits = (unsigned int*)(meanv + (size_t)B * C);            // 3.2 MB

    k_mean_copy <<<dim3(B, NCHUNK), 256, 0, stream>>>(x, out, partial);
    k_mean_final<<<dim3(B),         256, 0, stream>>>(partial, meanv);
    k_bits      <<<dim3(B, W),       64, 0, stream>>>(x, meanv, bits);
    k_mask_fix  <<<dim3(B, C / TC), 256, 0, stream>>>(bits, out);
}